// Round 1
// baseline (38.663 us; speedup 1.0000x reference)
//
#include <hip/hip_runtime.h>

// ExodusNet: per-timestep 32-tap dense projection + LIF scan (membrane subtract).
// x: [N=16384, C=2, H=4, W=4, T=100] f32 (t innermost, chw stride = 100)
// W: [1,2,4,4] f32 (32 taps)
// out: [N,1,1,1,T] f32 = spikes
//
// Memory-bound: 210 MB read + 6.5 MB write -> ~34 us floor at 6.3 TB/s.

#define T_STEPS 100
#define CHW     32
#define NPB     16      // neurons per block (4 per wave)
#define PITCH   101     // odd pitch -> <=2-way LDS bank aliasing (free)

__global__ __launch_bounds__(256, 4)
void exodus_fused(const float* __restrict__ x,
                  const float* __restrict__ W,
                  float* __restrict__ out) {
    __shared__ float s_in[NPB][PITCH];   // weighted input per (neuron, t)
    __shared__ float s_sp[NPB][PITCH];   // spikes per (neuron, t)

    const int tid    = threadIdx.x;
    const int lane   = tid & 63;
    const int wv     = tid >> 6;               // 0..3
    const int n_base = blockIdx.x * NPB;

    // Preload the 32 taps (uniform address -> SGPRs).
    float Wr[CHW];
    #pragma unroll
    for (int c = 0; c < CHW; ++c) Wr[c] = W[c];

    // ---- Phase A: weighted[n][t] = sum_c W[c] * x[n][c][t] ----
    // lane l (<50) owns t = 2l, 2l+1 via one float2 per chw row (coalesced,
    // each global_load_dwordx2 wave-instr covers exactly one 400B row).
    if (lane < T_STEPS / 2) {
        for (int i = 0; i < NPB / 4; ++i) {
            const int nl = wv * (NPB / 4) + i;
            const float* xp = x + (size_t)(n_base + nl) * (CHW * T_STEPS) + 2 * lane;
            float a0 = 0.f, a1 = 0.f;
            #pragma unroll
            for (int c = 0; c < CHW; ++c) {
                const float2 v = *reinterpret_cast<const float2*>(xp + c * T_STEPS);
                a0 += Wr[c] * v.x;
                a1 += Wr[c] * v.y;
            }
            s_in[nl][2 * lane]     = a0;
            s_in[nl][2 * lane + 1] = a1;
        }
    }
    __syncthreads();

    // ---- Phase B: LIF scan, sequential in t (nonlinear reset -> no prefix scan).
    // Lanes 0..3 of each wave scan that wave's own 4 neurons; 4 chains/block
    // run on 4 different SIMDs. LDS reads are address-independent of the v
    // chain, so they pipeline ahead of the dependent VALU chain.
    if (lane < NPB / 4) {
        const int nl = wv * (NPB / 4) + lane;
        const float A = 0.9048374180359595f;   // exp(-1/10), f64 -> f32 round
        const float B = 0.0951625819640404f;   // (1 - alpha) in f64 -> f32 round
        float v = 0.f;
        #pragma unroll 4
        for (int t = 0; t < T_STEPS; ++t) {
            v = A * v + B * s_in[nl][t];
            const float sp = (v >= 1.0f) ? 1.0f : 0.0f;
            v -= sp;                           // membrane subtract (THR = 1)
            s_sp[nl][t] = sp;
        }
    }
    __syncthreads();

    // ---- Phase C: coalesced write of the block's contiguous output slice.
    float* op = out + (size_t)n_base * T_STEPS;
    for (int k = tid; k < NPB * T_STEPS; k += 256) {
        op[k] = s_sp[k / T_STEPS][k % T_STEPS];
    }
}

extern "C" void kernel_launch(void* const* d_in, const int* in_sizes, int n_in,
                              void* d_out, int out_size, void* d_ws, size_t ws_size,
                              hipStream_t stream) {
    const float* x = (const float*)d_in[0];
    const float* W = (const float*)d_in[1];
    float* out = (float*)d_out;

    const int N = in_sizes[0] / (CHW * T_STEPS);   // 16384
    const int grid = N / NPB;                      // 1024 blocks
    exodus_fused<<<grid, 256, 0, stream>>>(x, W, out);
}

// Round 2
// 37.266 us; speedup vs baseline: 1.0375x; 1.0375x over previous
//
#include <hip/hip_runtime.h>

// ExodusNet: per-timestep 32-tap dense projection + LIF scan (membrane subtract).
// x: [N=16384, C=2, H=4, W=4, T=100] f32 (t innermost, chw stride = 100)
// W: [1,2,4,4] f32 (32 taps) -> uniform-address, lands in SGPRs
// out: [N,1,1,1,T] f32 = spikes
//
// Memory-bound: 210 MB read + 6.5 MB write. R1: 38.7 us (5.6 TB/s).
// R2 changes: grid 1024->2048 (2 rounds -> phase stagger hides B/C tails),
// register double-buffered load stream (4 chunks of 16xfloat2) so VMEM
// issue never stalls on the FMA reduction.

#define T_STEPS 100
#define CHW     32
#define NPW     2       // neurons per wave
#define NPB     8       // neurons per block (4 waves * NPW)
#define PITCH   101     // odd pitch -> <=2-way LDS bank aliasing (free)

__global__ __launch_bounds__(256, 4)
void exodus_fused(const float* __restrict__ x,
                  const float* __restrict__ W,
                  float* __restrict__ out) {
    __shared__ float s_in[NPB][PITCH];   // weighted input per (neuron, t)
    __shared__ float s_sp[NPB][PITCH];   // spikes per (neuron, t)

    const int tid    = threadIdx.x;
    const int lane   = tid & 63;
    const int wv     = tid >> 6;               // 0..3
    const int n_base = blockIdx.x * NPB;

    // 32 taps, uniform address -> scalar loads / SGPRs.
    float Wr[CHW];
    #pragma unroll
    for (int c = 0; c < CHW; ++c) Wr[c] = W[c];

    // ---- Phase A: weighted[n][t] = sum_c W[c] * x[n][c][t] ----
    // lane l (<50) owns t = 2l, 2l+1. Wave streams its 2 neurons as 4 chunks
    // of 16 rows, double-buffered in registers: chunk k+1's loads are issued
    // before chunk k's FMAs consume, so the memory pipe never idles.
    if (lane < T_STEPS / 2) {
        const float* xw = x + (size_t)(n_base + wv * NPW) * (CHW * T_STEPS) + 2 * lane;
        const int NSTR = CHW * T_STEPS;        // neuron stride in floats

        float2 bA[16], bB[16];
        #pragma unroll
        for (int j = 0; j < 16; ++j)           // chunk0: n0, c=0..15
            bA[j] = *reinterpret_cast<const float2*>(xw + j * T_STEPS);
        #pragma unroll
        for (int j = 0; j < 16; ++j)           // chunk1: n0, c=16..31
            bB[j] = *reinterpret_cast<const float2*>(xw + (16 + j) * T_STEPS);

        float n0x = 0.f, n0y = 0.f;
        #pragma unroll
        for (int j = 0; j < 16; ++j) {         // consume chunk0
            n0x = fmaf(Wr[j], bA[j].x, n0x);
            n0y = fmaf(Wr[j], bA[j].y, n0y);
        }
        #pragma unroll
        for (int j = 0; j < 16; ++j)           // chunk2: n1, c=0..15
            bA[j] = *reinterpret_cast<const float2*>(xw + NSTR + j * T_STEPS);
        #pragma unroll
        for (int j = 0; j < 16; ++j) {         // consume chunk1 -> n0 done
            n0x = fmaf(Wr[16 + j], bB[j].x, n0x);
            n0y = fmaf(Wr[16 + j], bB[j].y, n0y);
        }
        s_in[wv * NPW + 0][2 * lane]     = n0x;
        s_in[wv * NPW + 0][2 * lane + 1] = n0y;

        #pragma unroll
        for (int j = 0; j < 16; ++j)           // chunk3: n1, c=16..31
            bB[j] = *reinterpret_cast<const float2*>(xw + NSTR + (16 + j) * T_STEPS);

        float n1x = 0.f, n1y = 0.f;
        #pragma unroll
        for (int j = 0; j < 16; ++j) {         // consume chunk2
            n1x = fmaf(Wr[j], bA[j].x, n1x);
            n1y = fmaf(Wr[j], bA[j].y, n1y);
        }
        #pragma unroll
        for (int j = 0; j < 16; ++j) {         // consume chunk3 -> n1 done
            n1x = fmaf(Wr[16 + j], bB[j].x, n1x);
            n1y = fmaf(Wr[16 + j], bB[j].y, n1y);
        }
        s_in[wv * NPW + 1][2 * lane]     = n1x;
        s_in[wv * NPW + 1][2 * lane + 1] = n1y;
    }
    __syncthreads();

    // ---- Phase B: LIF scan, sequential in t (nonlinear reset -> serial).
    // Lanes 0..1 of each wave scan the wave's 2 neurons.
    if (lane < NPW) {
        const int nl = wv * NPW + lane;
        const float A = 0.9048374180359595f;   // exp(-1/10) rounded to f32
        const float B = 0.0951625819640404f;   // 1 - alpha
        float v = 0.f;
        #pragma unroll 4
        for (int t = 0; t < T_STEPS; ++t) {
            v = fmaf(A, v, B * s_in[nl][t]);
            const float sp = (v >= 1.0f) ? 1.0f : 0.0f;
            v -= sp;                           // membrane subtract (THR = 1)
            s_sp[nl][t] = sp;
        }
    }
    __syncthreads();

    // ---- Phase C: coalesced write of the block's contiguous output slice.
    float* op = out + (size_t)n_base * T_STEPS;
    for (int k = tid; k < NPB * T_STEPS; k += 256) {
        op[k] = s_sp[k / T_STEPS][k % T_STEPS];
    }
}

extern "C" void kernel_launch(void* const* d_in, const int* in_sizes, int n_in,
                              void* d_out, int out_size, void* d_ws, size_t ws_size,
                              hipStream_t stream) {
    const float* x = (const float*)d_in[0];
    const float* W = (const float*)d_in[1];
    float* out = (float*)d_out;

    const int N = in_sizes[0] / (CHW * T_STEPS);   // 16384
    const int grid = N / NPB;                      // 2048 blocks
    exodus_fused<<<grid, 256, 0, stream>>>(x, W, out);
}